// Round 8
// baseline (199.659 us; speedup 1.0000x reference)
//
#include <hip/hip_runtime.h>

typedef short bf16x8 __attribute__((ext_vector_type(8)));   // 8 bf16 in 4 VGPRs
typedef float f32x4  __attribute__((ext_vector_type(4)));
typedef int   i32x4  __attribute__((ext_vector_type(4)));
typedef unsigned int u32x2 __attribute__((ext_vector_type(2)));

#define DEV static __device__ __forceinline__
#define LOG2E 1.4426950408889634f

DEV float bfu_to_f(unsigned short s) { return __builtin_bit_cast(float, (unsigned int)s << 16); }
DEV unsigned short f_to_bf(float f) {                 // RNE fp32 -> bf16
  unsigned int u = __builtin_bit_cast(unsigned int, f);
  u += 0x7fffu + ((u >> 16) & 1u);
  return (unsigned short)(u >> 16);
}
DEV unsigned int pack_bf_rne(float lo, float hi) {
  return (unsigned int)f_to_bf(lo) | ((unsigned int)f_to_bf(hi) << 16);
}
// RTZ pack of two f32 -> (bf16(hi)<<16)|bf16(lo): one v_perm_b32
DEV unsigned int pack_bf_rtz(float lo, float hi) {
#if __has_builtin(__builtin_amdgcn_perm)
  return __builtin_amdgcn_perm(__builtin_bit_cast(unsigned int, hi),
                               __builtin_bit_cast(unsigned int, lo), 0x07060302u);
#else
  return (__builtin_bit_cast(unsigned int, hi) & 0xffff0000u) |
         (__builtin_bit_cast(unsigned int, lo) >> 16);
#endif
}

// dtype discriminator: adj[0][0] == 1.0 exactly. fp32 word0 == 0x3F800000;
// bf16 word0 low halfword = 0x3F80 != 0 -> never equal.
DEV bool detect_f32(const void* adj) { return ((const float*)adj)[0] == 1.0f; }

template<bool F32> DEV float ldS(const void* p, size_t i) {
  if constexpr (F32) return ((const float*)p)[i];
  else               return bfu_to_f(((const unsigned short*)p)[i]);
}
template<bool F32> DEV void ld8f(const void* p, size_t i, float* o) {
  if constexpr (F32) {
    const float* f = (const float*)p + i;
    f32x4 a = *(const f32x4*)f, b = *(const f32x4*)(f + 4);
    o[0]=a[0]; o[1]=a[1]; o[2]=a[2]; o[3]=a[3];
    o[4]=b[0]; o[5]=b[1]; o[6]=b[2]; o[7]=b[3];
  } else {
    i32x4 w = *(const i32x4*)((const unsigned short*)p + i);
#pragma unroll
    for (int k = 0; k < 4; ++k) {
      unsigned int u = (unsigned int)w[k];
      o[2*k]   = __builtin_bit_cast(float, u << 16);
      o[2*k+1] = __builtin_bit_cast(float, u & 0xffff0000u);
    }
  }
}
template<bool F32> DEV bf16x8 ldfrag(const void* p, size_t i) {
  if constexpr (F32) {
    float o[8]; ld8f<true>(p, i, o);
    union { bf16x8 v; unsigned short u[8]; } r;
#pragma unroll
    for (int k = 0; k < 8; ++k) r.u[k] = f_to_bf(o[k]);
    return r.v;
  } else {
    return __builtin_bit_cast(bf16x8, *(const i32x4*)((const unsigned short*)p + i));
  }
}

// ---------------- Kernel 1: hT[(b*4+hh)*32+d][n] = (x@W^T) transposed, bf16 ----------
template<bool F32> DEV void k_h_body(const void* __restrict__ x, const void* __restrict__ W,
                                     unsigned short* __restrict__ hT,
                                     unsigned short (&t_s)[16][136]) {
  const int tid = threadIdx.x, lane = tid & 63, wave = tid >> 6;
  const int nt = blockIdx.x >> 3, ct = blockIdx.x & 7;    // 128 nt x 8 ct
  const int m = lane & 15, q = lane >> 4;
  bf16x8 wf[4];
#pragma unroll
  for (int k = 0; k < 4; ++k)
    wf[k] = ldfrag<F32>(W, (size_t)(ct * 16 + m) * 128 + q * 8 + k * 32);
#pragma unroll
  for (int s = 0; s < 2; ++s) {
    const int nsub = wave * 2 + s;
    const size_t xr = (size_t)(nt * 128 + nsub * 16 + m) * 128 + q * 8;
    f32x4 acc = {0.f, 0.f, 0.f, 0.f};
#pragma unroll
    for (int k = 0; k < 4; ++k)
      acc = __builtin_amdgcn_mfma_f32_16x16x32_bf16(ldfrag<F32>(x, xr + k * 32), wf[k],
                                                    acc, 0, 0, 0);
    u32x2 w2; w2[0] = pack_bf_rne(acc[0], acc[1]); w2[1] = pack_bf_rne(acc[2], acc[3]);
    *(u32x2*)&t_s[m][nsub * 16 + q * 4] = w2;
  }
  __syncthreads();
  const int row = tid >> 4, c8 = tid & 15;
  const int chg = ct * 16 + row, hh = chg >> 5, dloc = chg & 31;
  const int ng = nt * 128 + c8 * 8, b = ng >> 11, nl = ng & 2047;
  i32x4 v = *(const i32x4*)&t_s[row][c8 * 8];
  *(i32x4*)(hT + ((size_t)((b * 4 + hh) * 32 + dloc)) * 2048 + nl) = v;
}
__global__ __launch_bounds__(256) void k_h(const void* x, const void* W,
                                           unsigned short* hT, const void* adj) {
  __shared__ __align__(16) unsigned short t_s[16][136];   // shared across both instantiations
  if (detect_f32(adj)) k_h_body<true>(x, W, hT, t_s); else k_h_body<false>(x, W, hT, t_s);
}

// ---------------- Kernel 1b: src/dst projections (pre-scaled by log2e) ----------------
template<bool F32> DEV void k_sd_body(const unsigned short* __restrict__ hT,
                                      const void* __restrict__ a_src, const void* __restrict__ a_dst,
                                      float* __restrict__ srcv, float* __restrict__ dstv) {
  const int t = blockIdx.x * 256 + threadIdx.x;      // (bh, n), n fastest
  const int n = t & 2047, bh = t >> 11, hh = bh & 3;
  const unsigned short* col = hT + (size_t)bh * 32 * 2048 + n;
  float s = 0.f, d = 0.f;
#pragma unroll
  for (int dd = 0; dd < 32; ++dd) {
    const float v = bfu_to_f(col[(size_t)dd * 2048]);
    s += v * ldS<F32>(a_src, hh * 32 + dd);
    d += v * ldS<F32>(a_dst, hh * 32 + dd);
  }
  srcv[t] = s * LOG2E; dstv[t] = d * LOG2E;          // exp(x) = exp2(x*log2e)
}
__global__ __launch_bounds__(256) void k_sd(const unsigned short* hT, const void* a_src,
                                            const void* a_dst, float* srcv, float* dstv,
                                            const void* adj) {
  if (detect_f32(adj)) k_sd_body<true>(hT, a_src, a_dst, srcv, dstv);
  else                 k_sd_body<false>(hT, a_src, a_dst, srcv, dstv);
}

// ---------------- Kernel 2: LDS double-buffered flash GAT attention ----------------
// Block = (bh, i64-tile), 4 waves. adj + V^T staged to LDS coalesced, double-buffered,
// one barrier per 128-j chunk. dst' read from global (L1-resident 8KB row, quad-broadcast).
// attn_ij = A_ij * exp2(leaky(src'_i+dst'_j)) / den_i  (src/dst pre-scaled by log2e).
struct SmemAttn {
  unsigned short adj[2][64][136];   // [buf][i-local][j-local], stride 68 dw (=4 mod 32)
  unsigned short vt[2][32][136];    // [buf][d][j-local]
};                                  // 52224 B -> 3 blocks/CU

template<bool F32> DEV void k_attn_body(SmemAttn& sm, const void* __restrict__ adjv,
                                        const unsigned short* __restrict__ hT,
                                        const float* __restrict__ srcv,
                                        const float* __restrict__ dstv,
                                        unsigned short* __restrict__ ao) {
  const int tid = threadIdx.x, lane = tid & 63, wave = tid >> 6;
  const int bh = blockIdx.x & 31, i64 = blockIdx.x >> 5;   // bh-fast: adjacent blocks share adj
  const int b = bh >> 2, hh = bh & 3;
  const int m = lane & 15, q = lane >> 4;
  const int i0 = i64 * 64;
  const int il = wave * 16 + m;                            // lane's local i-row (0..63)
  const int srow = tid >> 4, scol = (tid & 15) * 8;        // staging map: 16 thr/row, 8 elems

  const float* dstj = dstv + bh * 2048;                    // global dst' row (L1 after 1st touch)

  f32x4 fr[8];   // F32 adj prefetch regs
  i32x4 br[4];   // BF16 adj prefetch regs
  i32x4 vr[2];   // V^T prefetch regs

  // ---- prologue: stage chunk 0 into buf 0 ----
#pragma unroll
  for (int p = 0; p < 4; ++p) {
    const size_t g = (size_t)(i0 + p * 16 + srow) * 2048 + scol;
    if constexpr (F32) {
      fr[2*p]   = *(const f32x4*)((const float*)adjv + g);
      fr[2*p+1] = *(const f32x4*)((const float*)adjv + g + 4);
    } else {
      br[p] = *(const i32x4*)((const unsigned short*)adjv + g);
    }
  }
#pragma unroll
  for (int p = 0; p < 2; ++p)
    vr[p] = *(const i32x4*)(hT + ((size_t)bh * 32 + p * 16 + srow) * 2048 + scol);
#pragma unroll
  for (int p = 0; p < 4; ++p) {
    i32x4 w;
    if constexpr (F32) {
      w[0] = (int)pack_bf_rtz(fr[2*p][0], fr[2*p][1]);
      w[1] = (int)pack_bf_rtz(fr[2*p][2], fr[2*p][3]);
      w[2] = (int)pack_bf_rtz(fr[2*p+1][0], fr[2*p+1][1]);
      w[3] = (int)pack_bf_rtz(fr[2*p+1][2], fr[2*p+1][3]);
    } else w = br[p];
    *(i32x4*)&sm.adj[0][p * 16 + srow][scol] = w;
  }
#pragma unroll
  for (int p = 0; p < 2; ++p) *(i32x4*)&sm.vt[0][p * 16 + srow][scol] = vr[p];
  __syncthreads();

  const float src_i = srcv[bh * 2048 + i0 + il];
  f32x4 acc0 = {0.f,0.f,0.f,0.f}, acc1 = {0.f,0.f,0.f,0.f};
  float den = 0.f;

  for (int c = 0; c < 16; ++c) {
    const int cb = c & 1;
    const bool pf = (c < 15);
    if (pf) {                                   // issue chunk c+1 loads (coalesced)
      const int j1 = (c + 1) * 128;
#pragma unroll
      for (int p = 0; p < 4; ++p) {
        const size_t g = (size_t)(i0 + p * 16 + srow) * 2048 + j1 + scol;
        if constexpr (F32) {
          fr[2*p]   = *(const f32x4*)((const float*)adjv + g);
          fr[2*p+1] = *(const f32x4*)((const float*)adjv + g + 4);
        } else {
          br[p] = *(const i32x4*)((const unsigned short*)adjv + g);
        }
      }
#pragma unroll
      for (int p = 0; p < 2; ++p)
        vr[p] = *(const i32x4*)(hT + ((size_t)bh * 32 + p * 16 + srow) * 2048 + j1 + scol);
    }
    // ---- compute 4 x 32-j on buf cb ----
#pragma unroll
    for (int jc = 0; jc < 4; ++jc) {
      const int jq = jc * 32 + q * 8;
      i32x4 aw = *(const i32x4*)&sm.adj[cb][il][jq];
      f32x4 d0 = *(const f32x4*)(dstj + c * 128 + jq);
      f32x4 d1 = *(const f32x4*)(dstj + c * 128 + jq + 4);
      bf16x8 A0 = *(const bf16x8*)&sm.vt[cb][m][jq];
      bf16x8 A1 = *(const bf16x8*)&sm.vt[cb][16 + m][jq];
      float a[8];
#pragma unroll
      for (int t = 0; t < 4; ++t) {
        unsigned int w = (unsigned int)aw[t];
        a[2*t]   = __builtin_bit_cast(float, w << 16);
        a[2*t+1] = __builtin_bit_cast(float, w & 0xffff0000u);
      }
      float p[8];
#pragma unroll
      for (int pp = 0; pp < 8; ++pp) {
        const float s = src_i + ((pp < 4) ? d0[pp] : d1[pp - 4]);     // log2-domain score
        const float l = fmaxf(s, 0.2f * s);                           // leaky: 0.2s>s iff s<0
        p[pp] = a[pp] * exp2f(l);                                     // bare v_exp_f32
      }
      den += ((p[0]+p[1]) + (p[2]+p[3])) + ((p[4]+p[5]) + (p[6]+p[7]));
      i32x4 pk4;
      pk4[0] = (int)pack_bf_rtz(p[0], p[1]);
      pk4[1] = (int)pack_bf_rtz(p[2], p[3]);
      pk4[2] = (int)pack_bf_rtz(p[4], p[5]);
      pk4[3] = (int)pack_bf_rtz(p[6], p[7]);
      const bf16x8 pkv = __builtin_bit_cast(bf16x8, pk4);
      acc0 = __builtin_amdgcn_mfma_f32_16x16x32_bf16(A0, pkv, acc0, 0, 0, 0);
      acc1 = __builtin_amdgcn_mfma_f32_16x16x32_bf16(A1, pkv, acc1, 0, 0, 0);
    }
    if (pf) {                                   // write chunk c+1 into the other buffer
      const int nb = cb ^ 1;
#pragma unroll
      for (int p = 0; p < 4; ++p) {
        i32x4 w;
        if constexpr (F32) {
          w[0] = (int)pack_bf_rtz(fr[2*p][0], fr[2*p][1]);
          w[1] = (int)pack_bf_rtz(fr[2*p][2], fr[2*p][3]);
          w[2] = (int)pack_bf_rtz(fr[2*p+1][0], fr[2*p+1][1]);
          w[3] = (int)pack_bf_rtz(fr[2*p+1][2], fr[2*p+1][3]);
        } else w = br[p];
        *(i32x4*)&sm.adj[nb][p * 16 + srow][scol] = w;
      }
#pragma unroll
      for (int p = 0; p < 2; ++p) *(i32x4*)&sm.vt[nb][p * 16 + srow][scol] = vr[p];
    }
    __syncthreads();
  }

  den += __shfl_xor(den, 16, 64);                // row i=m partials live on the 4 q-lanes
  den += __shfl_xor(den, 32, 64);
  const float inv = 1.f / fmaxf(den, 1e-20f);

  // D: col = m = i, row = q*4+r = d. Lane writes channels q*4..+3 and 16+q*4..+3.
  unsigned short* op = ao + ((size_t)(b * 2048) + i0 + il) * 128 + hh * 32 + q * 4;
  u32x2 w0, w1;
  w0[0] = pack_bf_rne(acc0[0] * inv, acc0[1] * inv);
  w0[1] = pack_bf_rne(acc0[2] * inv, acc0[3] * inv);
  w1[0] = pack_bf_rne(acc1[0] * inv, acc1[1] * inv);
  w1[1] = pack_bf_rne(acc1[2] * inv, acc1[3] * inv);
  *(u32x2*)op        = w0;
  *(u32x2*)(op + 16) = w1;
}
__global__ __launch_bounds__(256) void k_attn(const void* adj, const unsigned short* hT,
                                              const float* srcv, const float* dstv,
                                              unsigned short* ao) {
  __shared__ __align__(16) SmemAttn sm;          // ONE allocation for both instantiations
  if (detect_f32(adj)) k_attn_body<true>(sm, adj, hT, srcv, dstv, ao);
  else                 k_attn_body<false>(sm, adj, hT, srcv, dstv, ao);
}

// ---------------- Kernel 3: y = LN(ao @ Wo^T + bo + x) ----------------
template<bool F32> DEV void k_out_body(const unsigned short* __restrict__ ao,
                                       const void* __restrict__ Wo, const void* __restrict__ bo,
                                       const void* __restrict__ x, const void* __restrict__ gamma,
                                       const void* __restrict__ beta, void* __restrict__ out,
                                       float (&y_s)[16][132]) {
  const int tid = threadIdx.x, lane = tid & 63, wave = tid >> 6;
  const int m = lane & 15, q = lane >> 4;
  const int rbase = blockIdx.x * 16;
  bf16x8 af[4];
#pragma unroll
  for (int k = 0; k < 4; ++k)
    af[k] = ldfrag<false>(ao, ((size_t)(rbase + m)) * 128 + q * 8 + k * 32);
  f32x4 acc[2] = {{0.f,0.f,0.f,0.f},{0.f,0.f,0.f,0.f}};
#pragma unroll
  for (int ct = 0; ct < 2; ++ct) {
    const size_t wrow = (size_t)(wave * 32 + ct * 16 + m) * 128 + q * 8;
#pragma unroll
    for (int k = 0; k < 4; ++k)
      acc[ct] = __builtin_amdgcn_mfma_f32_16x16x32_bf16(af[k], ldfrag<F32>(Wo, wrow + k * 32),
                                                        acc[ct], 0, 0, 0);
  }
#pragma unroll
  for (int ct = 0; ct < 2; ++ct) {
    const int c = wave * 32 + ct * 16 + m;
    const float bov = ldS<F32>(bo, c);
#pragma unroll
    for (int r = 0; r < 4; ++r) {
      const int row = q * 4 + r;
      y_s[row][c] = acc[ct][r] + bov + ldS<F32>(x, (size_t)(rbase + row) * 128 + c);
    }
  }
  __syncthreads();
  const int r = tid >> 4, c16 = tid & 15;
  float vals[8], sum = 0.f, sq = 0.f;
#pragma unroll
  for (int k = 0; k < 8; ++k) {
    const float v = y_s[r][c16 * 8 + k];
    vals[k] = v; sum += v; sq += v * v;
  }
#pragma unroll
  for (int msk = 1; msk < 16; msk <<= 1) {
    sum += __shfl_xor(sum, msk, 16);
    sq  += __shfl_xor(sq,  msk, 16);
  }
  const float mu  = sum * (1.f / 128.f);
  const float var = fmaxf(sq * (1.f / 128.f) - mu * mu, 0.f);
  const float rstd = rsqrtf(var + 1e-5f);
  float o[8];
#pragma unroll
  for (int k = 0; k < 8; ++k) {
    const int c = c16 * 8 + k;
    o[k] = (vals[k] - mu) * rstd * ldS<F32>(gamma, c) + ldS<F32>(beta, c);
  }
  const size_t obase = (size_t)(rbase + r) * 128 + c16 * 8;
  if constexpr (F32) {
    float* op = (float*)out + obase;
    f32x4 w0 = {o[0],o[1],o[2],o[3]}, w1 = {o[4],o[5],o[6],o[7]};
    *(f32x4*)op = w0; *(f32x4*)(op + 4) = w1;
  } else {
    union { unsigned short u[8]; i32x4 v; } ob;
#pragma unroll
    for (int k = 0; k < 8; ++k) ob.u[k] = f_to_bf(o[k]);
    *(i32x4*)((unsigned short*)out + obase) = ob.v;
  }
}
__global__ __launch_bounds__(256) void k_out(const unsigned short* ao, const void* Wo,
                                             const void* bo, const void* x, const void* gamma,
                                             const void* beta, void* out, const void* adj) {
  __shared__ __align__(16) float y_s[16][132];   // shared across both instantiations
  if (detect_f32(adj)) k_out_body<true>(ao, Wo, bo, x, gamma, beta, out, y_s);
  else                 k_out_body<false>(ao, Wo, bo, x, gamma, beta, out, y_s);
}

// ---------------- launch ----------------
extern "C" void kernel_launch(void* const* d_in, const int* in_sizes, int n_in,
                              void* d_out, int out_size, void* d_ws, size_t ws_size,
                              hipStream_t stream) {
  const void* x     = d_in[0];
  const void* adj   = d_in[1];
  const void* W     = d_in[2];
  const void* a_src = d_in[3];
  const void* a_dst = d_in[4];
  const void* Wo    = d_in[5];
  const void* bo    = d_in[6];
  const void* gamma = d_in[7];
  const void* beta  = d_in[8];

  char* ws = (char*)d_ws;
  unsigned short* hT_ws  = (unsigned short*)ws;              // 4,194,304 B  bf16 hT (BH*32, N)
  unsigned short* ao_ws  = (unsigned short*)(ws + 4194304);  // 4,194,304 B  bf16 attn out (B,N,128)
  float*          src_ws = (float*)(ws + 8388608);           // 262,144 B    fp32 src' (BH,N)
  float*          dst_ws = (float*)(ws + 8650752);           // 262,144 B    fp32 dst' (BH,N)

  k_h   <<<1024, 256, 0, stream>>>(x, W, hT_ws, adj);
  k_sd  <<<256,  256, 0, stream>>>(hT_ws, a_src, a_dst, src_ws, dst_ws, adj);
  k_attn<<<1024, 256, 0, stream>>>(adj, hT_ws, src_ws, dst_ws, ao_ws);
  k_out <<<1024, 256, 0, stream>>>(ao_ws, Wo, bo, x, gamma, beta, d_out, adj);
}

// Round 9
// 175.822 us; speedup vs baseline: 1.1356x; 1.1356x over previous
//
#include <hip/hip_runtime.h>

typedef short bf16x8 __attribute__((ext_vector_type(8)));   // 8 bf16 in 4 VGPRs
typedef float f32x4  __attribute__((ext_vector_type(4)));
typedef int   i32x4  __attribute__((ext_vector_type(4)));
typedef unsigned int u32x2 __attribute__((ext_vector_type(2)));

#define DEV static __device__ __forceinline__
#define LOG2E 1.4426950408889634f

DEV float bfu_to_f(unsigned short s) { return __builtin_bit_cast(float, (unsigned int)s << 16); }
DEV unsigned short f_to_bf(float f) {                 // RNE fp32 -> bf16
  unsigned int u = __builtin_bit_cast(unsigned int, f);
  u += 0x7fffu + ((u >> 16) & 1u);
  return (unsigned short)(u >> 16);
}
DEV unsigned int pack_bf_rne(float lo, float hi) {
  return (unsigned int)f_to_bf(lo) | ((unsigned int)f_to_bf(hi) << 16);
}
// RTZ pack of two f32 -> (bf16(hi)<<16)|bf16(lo): one v_perm_b32
DEV unsigned int pack_bf_rtz(float lo, float hi) {
#if __has_builtin(__builtin_amdgcn_perm)
  return __builtin_amdgcn_perm(__builtin_bit_cast(unsigned int, hi),
                               __builtin_bit_cast(unsigned int, lo), 0x07060302u);
#else
  return (__builtin_bit_cast(unsigned int, hi) & 0xffff0000u) |
         (__builtin_bit_cast(unsigned int, lo) >> 16);
#endif
}

// dtype discriminator: adj[0][0] == 1.0 exactly. fp32 word0 == 0x3F800000;
// bf16 word0 low halfword = 0x3F80 != 0 -> never equal.
DEV bool detect_f32(const void* adj) { return ((const float*)adj)[0] == 1.0f; }

template<bool F32> DEV float ldS(const void* p, size_t i) {
  if constexpr (F32) return ((const float*)p)[i];
  else               return bfu_to_f(((const unsigned short*)p)[i]);
}
template<bool F32> DEV void ld8f(const void* p, size_t i, float* o) {
  if constexpr (F32) {
    const float* f = (const float*)p + i;
    f32x4 a = *(const f32x4*)f, b = *(const f32x4*)(f + 4);
    o[0]=a[0]; o[1]=a[1]; o[2]=a[2]; o[3]=a[3];
    o[4]=b[0]; o[5]=b[1]; o[6]=b[2]; o[7]=b[3];
  } else {
    i32x4 w = *(const i32x4*)((const unsigned short*)p + i);
#pragma unroll
    for (int k = 0; k < 4; ++k) {
      unsigned int u = (unsigned int)w[k];
      o[2*k]   = __builtin_bit_cast(float, u << 16);
      o[2*k+1] = __builtin_bit_cast(float, u & 0xffff0000u);
    }
  }
}
template<bool F32> DEV bf16x8 ldfrag(const void* p, size_t i) {
  if constexpr (F32) {
    float o[8]; ld8f<true>(p, i, o);
    union { bf16x8 v; unsigned short u[8]; } r;
#pragma unroll
    for (int k = 0; k < 8; ++k) r.u[k] = f_to_bf(o[k]);
    return r.v;
  } else {
    return __builtin_bit_cast(bf16x8, *(const i32x4*)((const unsigned short*)p + i));
  }
}

// ---------------- Kernel 1: hT[(b*4+hh)*32+d][n] = (x@W^T) transposed, bf16 ----------
template<bool F32> DEV void k_h_body(const void* __restrict__ x, const void* __restrict__ W,
                                     unsigned short* __restrict__ hT,
                                     unsigned short (&t_s)[16][136]) {
  const int tid = threadIdx.x, lane = tid & 63, wave = tid >> 6;
  const int nt = blockIdx.x >> 3, ct = blockIdx.x & 7;    // 128 nt x 8 ct
  const int m = lane & 15, q = lane >> 4;
  bf16x8 wf[4];
#pragma unroll
  for (int k = 0; k < 4; ++k)
    wf[k] = ldfrag<F32>(W, (size_t)(ct * 16 + m) * 128 + q * 8 + k * 32);
#pragma unroll
  for (int s = 0; s < 2; ++s) {
    const int nsub = wave * 2 + s;
    const size_t xr = (size_t)(nt * 128 + nsub * 16 + m) * 128 + q * 8;
    f32x4 acc = {0.f, 0.f, 0.f, 0.f};
#pragma unroll
    for (int k = 0; k < 4; ++k)
      acc = __builtin_amdgcn_mfma_f32_16x16x32_bf16(ldfrag<F32>(x, xr + k * 32), wf[k],
                                                    acc, 0, 0, 0);
    u32x2 w2; w2[0] = pack_bf_rne(acc[0], acc[1]); w2[1] = pack_bf_rne(acc[2], acc[3]);
    *(u32x2*)&t_s[m][nsub * 16 + q * 4] = w2;
  }
  __syncthreads();
  const int row = tid >> 4, c8 = tid & 15;
  const int chg = ct * 16 + row, hh = chg >> 5, dloc = chg & 31;
  const int ng = nt * 128 + c8 * 8, b = ng >> 11, nl = ng & 2047;
  i32x4 v = *(const i32x4*)&t_s[row][c8 * 8];
  *(i32x4*)(hT + ((size_t)((b * 4 + hh) * 32 + dloc)) * 2048 + nl) = v;
}
__global__ __launch_bounds__(256) void k_h(const void* x, const void* W,
                                           unsigned short* hT, const void* adj) {
  __shared__ __align__(16) unsigned short t_s[16][136];   // shared across both instantiations
  if (detect_f32(adj)) k_h_body<true>(x, W, hT, t_s); else k_h_body<false>(x, W, hT, t_s);
}

// ---------------- Kernel 1b: src/dst projections (pre-scaled by log2e) ----------------
template<bool F32> DEV void k_sd_body(const unsigned short* __restrict__ hT,
                                      const void* __restrict__ a_src, const void* __restrict__ a_dst,
                                      float* __restrict__ srcv, float* __restrict__ dstv) {
  const int t = blockIdx.x * 256 + threadIdx.x;      // (bh, n), n fastest
  const int n = t & 2047, bh = t >> 11, hh = bh & 3;
  const unsigned short* col = hT + (size_t)bh * 32 * 2048 + n;
  float s = 0.f, d = 0.f;
#pragma unroll
  for (int dd = 0; dd < 32; ++dd) {
    const float v = bfu_to_f(col[(size_t)dd * 2048]);
    s += v * ldS<F32>(a_src, hh * 32 + dd);
    d += v * ldS<F32>(a_dst, hh * 32 + dd);
  }
  srcv[t] = s * LOG2E; dstv[t] = d * LOG2E;          // exp(x) = exp2(x*log2e)
}
__global__ __launch_bounds__(256) void k_sd(const unsigned short* hT, const void* a_src,
                                            const void* a_dst, float* srcv, float* dstv,
                                            const void* adj) {
  if (detect_f32(adj)) k_sd_body<true>(hT, a_src, a_dst, srcv, dstv);
  else                 k_sd_body<false>(hT, a_src, a_dst, srcv, dstv);
}

// ---------------- Kernel 2: LDS double-buffered flash GAT attention ----------------
// Block = (bh, i64-tile), 4 waves. adj + V^T staged to LDS coalesced, double-buffered,
// one barrier per 128-j chunk; dst' staged once in LDS (reads are same-address
// broadcasts across the 16 m-lanes -> free).  R8 lesson: inner-loop operands must be
// LDS- or register-staged; naked global loads in the jc loop expose L2 latency 64x.
// den is computed ON THE MFMA PIPE: acc2 with an all-ones A-fragment accumulates
// D[r][m] = sum_k P[m][k] -- the row denominator -- from the SAME bf16-rounded P
// fragment as the numerator (bit-identical semantics, zero VALU).
struct SmemAttn {
  unsigned short adj[2][64][136];   // [buf][i-local][j-local], stride 68 dw (=4 mod 32)
  unsigned short vt[2][32][136];    // [buf][d][j-local]
  float dst[2048];                  // full dst' row for this bh
};                                  // 60416 B -> 2 blocks/CU

template<bool F32> DEV void k_attn_body(SmemAttn& sm, const void* __restrict__ adjv,
                                        const unsigned short* __restrict__ hT,
                                        const float* __restrict__ srcv,
                                        const float* __restrict__ dstv,
                                        unsigned short* __restrict__ ao) {
  const int tid = threadIdx.x, lane = tid & 63, wave = tid >> 6;
  const int bh = blockIdx.x & 31, i64 = blockIdx.x >> 5;   // bh-fast: adjacent blocks share adj
  const int b = bh >> 2, hh = bh & 3;
  const int m = lane & 15, q = lane >> 4;
  const int i0 = i64 * 64;
  const int il = wave * 16 + m;                            // lane's local i-row (0..63)
  const int srow = tid >> 4, scol = (tid & 15) * 8;        // staging map: 16 thr/row, 8 elems

  // dst' for this bh: 2048 floats -> LDS, coalesced
  {
    const float* dp = dstv + bh * 2048 + tid * 8;
    *(f32x4*)&sm.dst[tid * 8]     = *(const f32x4*)dp;
    *(f32x4*)&sm.dst[tid * 8 + 4] = *(const f32x4*)(dp + 4);
  }

  f32x4 fr[8];   // F32 adj prefetch regs
  i32x4 br[4];   // BF16 adj prefetch regs
  i32x4 vr[2];   // V^T prefetch regs

  // ---- prologue: stage chunk 0 into buf 0 ----
#pragma unroll
  for (int p = 0; p < 4; ++p) {
    const size_t g = (size_t)(i0 + p * 16 + srow) * 2048 + scol;
    if constexpr (F32) {
      fr[2*p]   = *(const f32x4*)((const float*)adjv + g);
      fr[2*p+1] = *(const f32x4*)((const float*)adjv + g + 4);
    } else {
      br[p] = *(const i32x4*)((const unsigned short*)adjv + g);
    }
  }
#pragma unroll
  for (int p = 0; p < 2; ++p)
    vr[p] = *(const i32x4*)(hT + ((size_t)bh * 32 + p * 16 + srow) * 2048 + scol);
#pragma unroll
  for (int p = 0; p < 4; ++p) {
    i32x4 w;
    if constexpr (F32) {
      w[0] = (int)pack_bf_rtz(fr[2*p][0], fr[2*p][1]);
      w[1] = (int)pack_bf_rtz(fr[2*p][2], fr[2*p][3]);
      w[2] = (int)pack_bf_rtz(fr[2*p+1][0], fr[2*p+1][1]);
      w[3] = (int)pack_bf_rtz(fr[2*p+1][2], fr[2*p+1][3]);
    } else w = br[p];
    *(i32x4*)&sm.adj[0][p * 16 + srow][scol] = w;
  }
#pragma unroll
  for (int p = 0; p < 2; ++p) *(i32x4*)&sm.vt[0][p * 16 + srow][scol] = vr[p];
  __syncthreads();

  const float src_i = srcv[bh * 2048 + i0 + il];
  f32x4 acc0 = {0.f,0.f,0.f,0.f}, acc1 = {0.f,0.f,0.f,0.f};
  f32x4 acc2 = {0.f,0.f,0.f,0.f};                          // den accumulator (ones-A MFMA)
  i32x4 ones4;                                             // bf16 1.0 x8 A-fragment
  ones4[0] = ones4[1] = ones4[2] = ones4[3] = (int)0x3F803F80u;
  const bf16x8 Aones = __builtin_bit_cast(bf16x8, ones4);

  for (int c = 0; c < 16; ++c) {
    const int cb = c & 1;
    const bool pf = (c < 15);
    if (pf) {                                   // issue chunk c+1 loads (coalesced)
      const int j1 = (c + 1) * 128;
#pragma unroll
      for (int p = 0; p < 4; ++p) {
        const size_t g = (size_t)(i0 + p * 16 + srow) * 2048 + j1 + scol;
        if constexpr (F32) {
          fr[2*p]   = *(const f32x4*)((const float*)adjv + g);
          fr[2*p+1] = *(const f32x4*)((const float*)adjv + g + 4);
        } else {
          br[p] = *(const i32x4*)((const unsigned short*)adjv + g);
        }
      }
#pragma unroll
      for (int p = 0; p < 2; ++p)
        vr[p] = *(const i32x4*)(hT + ((size_t)bh * 32 + p * 16 + srow) * 2048 + j1 + scol);
    }
    // ---- compute 4 x 32-j on buf cb ----
#pragma unroll
    for (int jc = 0; jc < 4; ++jc) {
      const int jq = jc * 32 + q * 8;
      i32x4 aw = *(const i32x4*)&sm.adj[cb][il][jq];
      f32x4 d0 = *(const f32x4*)&sm.dst[c * 128 + jq];
      f32x4 d1 = *(const f32x4*)&sm.dst[c * 128 + jq + 4];
      bf16x8 A0 = *(const bf16x8*)&sm.vt[cb][m][jq];
      bf16x8 A1 = *(const bf16x8*)&sm.vt[cb][16 + m][jq];
      float a[8];
#pragma unroll
      for (int t = 0; t < 4; ++t) {
        unsigned int w = (unsigned int)aw[t];
        a[2*t]   = __builtin_bit_cast(float, w << 16);
        a[2*t+1] = __builtin_bit_cast(float, w & 0xffff0000u);
      }
      float p[8];
#pragma unroll
      for (int pp = 0; pp < 8; ++pp) {
        const float s = src_i + ((pp < 4) ? d0[pp] : d1[pp - 4]);     // log2-domain score
        const float l = fmaxf(s, 0.2f * s);                           // leaky: 0.2s>s iff s<0
        p[pp] = a[pp] * exp2f(l);                                     // bare v_exp_f32
      }
      i32x4 pk4;
      pk4[0] = (int)pack_bf_rtz(p[0], p[1]);
      pk4[1] = (int)pack_bf_rtz(p[2], p[3]);
      pk4[2] = (int)pack_bf_rtz(p[4], p[5]);
      pk4[3] = (int)pack_bf_rtz(p[6], p[7]);
      const bf16x8 pkv = __builtin_bit_cast(bf16x8, pk4);
      acc0 = __builtin_amdgcn_mfma_f32_16x16x32_bf16(A0, pkv, acc0, 0, 0, 0);
      acc1 = __builtin_amdgcn_mfma_f32_16x16x32_bf16(A1, pkv, acc1, 0, 0, 0);
      acc2 = __builtin_amdgcn_mfma_f32_16x16x32_bf16(Aones, pkv, acc2, 0, 0, 0);
    }
    if (pf) {                                   // write chunk c+1 into the other buffer
      const int nb = cb ^ 1;
#pragma unroll
      for (int p = 0; p < 4; ++p) {
        i32x4 w;
        if constexpr (F32) {
          w[0] = (int)pack_bf_rtz(fr[2*p][0], fr[2*p][1]);
          w[1] = (int)pack_bf_rtz(fr[2*p][2], fr[2*p][3]);
          w[2] = (int)pack_bf_rtz(fr[2*p+1][0], fr[2*p+1][1]);
          w[3] = (int)pack_bf_rtz(fr[2*p+1][2], fr[2*p+1][3]);
        } else w = br[p];
        *(i32x4*)&sm.adj[nb][p * 16 + srow][scol] = w;
      }
#pragma unroll
      for (int p = 0; p < 2; ++p) *(i32x4*)&sm.vt[nb][p * 16 + srow][scol] = vr[p];
    }
    __syncthreads();
  }

  // den for row i=m is acc2[r] (identical for all r, all q) -- no shuffles needed.
  const float inv = 1.f / fmaxf(acc2[0], 1e-20f);

  // D: col = m = i, row = q*4+r = d. Lane writes channels q*4..+3 and 16+q*4..+3.
  unsigned short* op = ao + ((size_t)(b * 2048) + i0 + il) * 128 + hh * 32 + q * 4;
  u32x2 w0, w1;
  w0[0] = pack_bf_rne(acc0[0] * inv, acc0[1] * inv);
  w0[1] = pack_bf_rne(acc0[2] * inv, acc0[3] * inv);
  w1[0] = pack_bf_rne(acc1[0] * inv, acc1[1] * inv);
  w1[1] = pack_bf_rne(acc1[2] * inv, acc1[3] * inv);
  *(u32x2*)op        = w0;
  *(u32x2*)(op + 16) = w1;
}
__global__ __launch_bounds__(256) void k_attn(const void* adj, const unsigned short* hT,
                                              const float* srcv, const float* dstv,
                                              unsigned short* ao) {
  __shared__ __align__(16) SmemAttn sm;          // ONE allocation for both instantiations
  if (detect_f32(adj)) k_attn_body<true>(sm, adj, hT, srcv, dstv, ao);
  else                 k_attn_body<false>(sm, adj, hT, srcv, dstv, ao);
}

// ---------------- Kernel 3: y = LN(ao @ Wo^T + bo + x) ----------------
template<bool F32> DEV void k_out_body(const unsigned short* __restrict__ ao,
                                       const void* __restrict__ Wo, const void* __restrict__ bo,
                                       const void* __restrict__ x, const void* __restrict__ gamma,
                                       const void* __restrict__ beta, void* __restrict__ out,
                                       float (&y_s)[16][132]) {
  const int tid = threadIdx.x, lane = tid & 63, wave = tid >> 6;
  const int m = lane & 15, q = lane >> 4;
  const int rbase = blockIdx.x * 16;
  bf16x8 af[4];
#pragma unroll
  for (int k = 0; k < 4; ++k)
    af[k] = ldfrag<false>(ao, ((size_t)(rbase + m)) * 128 + q * 8 + k * 32);
  f32x4 acc[2] = {{0.f,0.f,0.f,0.f},{0.f,0.f,0.f,0.f}};
#pragma unroll
  for (int ct = 0; ct < 2; ++ct) {
    const size_t wrow = (size_t)(wave * 32 + ct * 16 + m) * 128 + q * 8;
#pragma unroll
    for (int k = 0; k < 4; ++k)
      acc[ct] = __builtin_amdgcn_mfma_f32_16x16x32_bf16(af[k], ldfrag<F32>(Wo, wrow + k * 32),
                                                        acc[ct], 0, 0, 0);
  }
#pragma unroll
  for (int ct = 0; ct < 2; ++ct) {
    const int c = wave * 32 + ct * 16 + m;
    const float bov = ldS<F32>(bo, c);
#pragma unroll
    for (int r = 0; r < 4; ++r) {
      const int row = q * 4 + r;
      y_s[row][c] = acc[ct][r] + bov + ldS<F32>(x, (size_t)(rbase + row) * 128 + c);
    }
  }
  __syncthreads();
  const int r = tid >> 4, c16 = tid & 15;
  float vals[8], sum = 0.f, sq = 0.f;
#pragma unroll
  for (int k = 0; k < 8; ++k) {
    const float v = y_s[r][c16 * 8 + k];
    vals[k] = v; sum += v; sq += v * v;
  }
#pragma unroll
  for (int msk = 1; msk < 16; msk <<= 1) {
    sum += __shfl_xor(sum, msk, 16);
    sq  += __shfl_xor(sq,  msk, 16);
  }
  const float mu  = sum * (1.f / 128.f);
  const float var = fmaxf(sq * (1.f / 128.f) - mu * mu, 0.f);
  const float rstd = rsqrtf(var + 1e-5f);
  float o[8];
#pragma unroll
  for (int k = 0; k < 8; ++k) {
    const int c = c16 * 8 + k;
    o[k] = (vals[k] - mu) * rstd * ldS<F32>(gamma, c) + ldS<F32>(beta, c);
  }
  const size_t obase = (size_t)(rbase + r) * 128 + c16 * 8;
  if constexpr (F32) {
    float* op = (float*)out + obase;
    f32x4 w0 = {o[0],o[1],o[2],o[3]}, w1 = {o[4],o[5],o[6],o[7]};
    *(f32x4*)op = w0; *(f32x4*)(op + 4) = w1;
  } else {
    union { unsigned short u[8]; i32x4 v; } ob;
#pragma unroll
    for (int k = 0; k < 8; ++k) ob.u[k] = f_to_bf(o[k]);
    *(i32x4*)((unsigned short*)out + obase) = ob.v;
  }
}
__global__ __launch_bounds__(256) void k_out(const unsigned short* ao, const void* Wo,
                                             const void* bo, const void* x, const void* gamma,
                                             const void* beta, void* out, const void* adj) {
  __shared__ __align__(16) float y_s[16][132];   // shared across both instantiations
  if (detect_f32(adj)) k_out_body<true>(ao, Wo, bo, x, gamma, beta, out, y_s);
  else                 k_out_body<false>(ao, Wo, bo, x, gamma, beta, out, y_s);
}

// ---------------- launch ----------------
extern "C" void kernel_launch(void* const* d_in, const int* in_sizes, int n_in,
                              void* d_out, int out_size, void* d_ws, size_t ws_size,
                              hipStream_t stream) {
  const void* x     = d_in[0];
  const void* adj   = d_in[1];
  const void* W     = d_in[2];
  const void* a_src = d_in[3];
  const void* a_dst = d_in[4];
  const void* Wo    = d_in[5];
  const void* bo    = d_in[6];
  const void* gamma = d_in[7];
  const void* beta  = d_in[8];

  char* ws = (char*)d_ws;
  unsigned short* hT_ws  = (unsigned short*)ws;              // 4,194,304 B  bf16 hT (BH*32, N)
  unsigned short* ao_ws  = (unsigned short*)(ws + 4194304);  // 4,194,304 B  bf16 attn out (B,N,128)
  float*          src_ws = (float*)(ws + 8388608);           // 262,144 B    fp32 src' (BH,N)
  float*          dst_ws = (float*)(ws + 8650752);           // 262,144 B    fp32 dst' (BH,N)

  k_h   <<<1024, 256, 0, stream>>>(x, W, hT_ws, adj);
  k_sd  <<<256,  256, 0, stream>>>(hT_ws, a_src, a_dst, src_ws, dst_ws, adj);
  k_attn<<<1024, 256, 0, stream>>>(adj, hT_ws, src_ws, dst_ws, ao_ws);
  k_out <<<1024, 256, 0, stream>>>(ao_ws, Wo, bo, x, gamma, beta, d_out, adj);
}

// Round 10
// 174.637 us; speedup vs baseline: 1.1433x; 1.0068x over previous
//
#include <hip/hip_runtime.h>

typedef short bf16x8 __attribute__((ext_vector_type(8)));   // 8 bf16 in 4 VGPRs
typedef float f32x4  __attribute__((ext_vector_type(4)));
typedef int   i32x4  __attribute__((ext_vector_type(4)));
typedef unsigned int u32x2 __attribute__((ext_vector_type(2)));

#define DEV static __device__ __forceinline__
#define LOG2E 1.4426950408889634f

DEV float bfu_to_f(unsigned short s) { return __builtin_bit_cast(float, (unsigned int)s << 16); }
DEV unsigned short f_to_bf(float f) {                 // RNE fp32 -> bf16
  unsigned int u = __builtin_bit_cast(unsigned int, f);
  u += 0x7fffu + ((u >> 16) & 1u);
  return (unsigned short)(u >> 16);
}
DEV unsigned int pack_bf_rne(float lo, float hi) {
  return (unsigned int)f_to_bf(lo) | ((unsigned int)f_to_bf(hi) << 16);
}
// RTZ pack of two f32 -> (bf16(hi)<<16)|bf16(lo): one v_perm_b32
DEV unsigned int pack_bf_rtz(float lo, float hi) {
#if __has_builtin(__builtin_amdgcn_perm)
  return __builtin_amdgcn_perm(__builtin_bit_cast(unsigned int, hi),
                               __builtin_bit_cast(unsigned int, lo), 0x07060302u);
#else
  return (__builtin_bit_cast(unsigned int, hi) & 0xffff0000u) |
         (__builtin_bit_cast(unsigned int, lo) >> 16);
#endif
}

// dtype discriminator: adj[0][0] == 1.0 exactly. fp32 word0 == 0x3F800000;
// bf16 word0 low halfword = 0x3F80 != 0 -> never equal.
DEV bool detect_f32(const void* adj) { return ((const float*)adj)[0] == 1.0f; }

template<bool F32> DEV float ldS(const void* p, size_t i) {
  if constexpr (F32) return ((const float*)p)[i];
  else               return bfu_to_f(((const unsigned short*)p)[i]);
}
template<bool F32> DEV void ld8f(const void* p, size_t i, float* o) {
  if constexpr (F32) {
    const float* f = (const float*)p + i;
    f32x4 a = *(const f32x4*)f, b = *(const f32x4*)(f + 4);
    o[0]=a[0]; o[1]=a[1]; o[2]=a[2]; o[3]=a[3];
    o[4]=b[0]; o[5]=b[1]; o[6]=b[2]; o[7]=b[3];
  } else {
    i32x4 w = *(const i32x4*)((const unsigned short*)p + i);
#pragma unroll
    for (int k = 0; k < 4; ++k) {
      unsigned int u = (unsigned int)w[k];
      o[2*k]   = __builtin_bit_cast(float, u << 16);
      o[2*k+1] = __builtin_bit_cast(float, u & 0xffff0000u);
    }
  }
}
template<bool F32> DEV bf16x8 ldfrag(const void* p, size_t i) {
  if constexpr (F32) {
    float o[8]; ld8f<true>(p, i, o);
    union { bf16x8 v; unsigned short u[8]; } r;
#pragma unroll
    for (int k = 0; k < 8; ++k) r.u[k] = f_to_bf(o[k]);
    return r.v;
  } else {
    return __builtin_bit_cast(bf16x8, *(const i32x4*)((const unsigned short*)p + i));
  }
}

// ---------------- Kernel 1: hT[(b*4+hh)*32+d][n] = (x@W^T) transposed, bf16 ----------
template<bool F32> DEV void k_h_body(const void* __restrict__ x, const void* __restrict__ W,
                                     unsigned short* __restrict__ hT,
                                     unsigned short (&t_s)[16][136]) {
  const int tid = threadIdx.x, lane = tid & 63, wave = tid >> 6;
  const int nt = blockIdx.x >> 3, ct = blockIdx.x & 7;    // 128 nt x 8 ct
  const int m = lane & 15, q = lane >> 4;
  bf16x8 wf[4];
#pragma unroll
  for (int k = 0; k < 4; ++k)
    wf[k] = ldfrag<F32>(W, (size_t)(ct * 16 + m) * 128 + q * 8 + k * 32);
#pragma unroll
  for (int s = 0; s < 2; ++s) {
    const int nsub = wave * 2 + s;
    const size_t xr = (size_t)(nt * 128 + nsub * 16 + m) * 128 + q * 8;
    f32x4 acc = {0.f, 0.f, 0.f, 0.f};
#pragma unroll
    for (int k = 0; k < 4; ++k)
      acc = __builtin_amdgcn_mfma_f32_16x16x32_bf16(ldfrag<F32>(x, xr + k * 32), wf[k],
                                                    acc, 0, 0, 0);
    u32x2 w2; w2[0] = pack_bf_rne(acc[0], acc[1]); w2[1] = pack_bf_rne(acc[2], acc[3]);
    *(u32x2*)&t_s[m][nsub * 16 + q * 4] = w2;
  }
  __syncthreads();
  const int row = tid >> 4, c8 = tid & 15;
  const int chg = ct * 16 + row, hh = chg >> 5, dloc = chg & 31;
  const int ng = nt * 128 + c8 * 8, b = ng >> 11, nl = ng & 2047;
  i32x4 v = *(const i32x4*)&t_s[row][c8 * 8];
  *(i32x4*)(hT + ((size_t)((b * 4 + hh) * 32 + dloc)) * 2048 + nl) = v;
}
__global__ __launch_bounds__(256) void k_h(const void* x, const void* W,
                                           unsigned short* hT, const void* adj) {
  __shared__ __align__(16) unsigned short t_s[16][136];   // shared across both instantiations
  if (detect_f32(adj)) k_h_body<true>(x, W, hT, t_s); else k_h_body<false>(x, W, hT, t_s);
}

// ---------------- Kernel 1b: src/dst projections (pre-scaled by log2e) ----------------
template<bool F32> DEV void k_sd_body(const unsigned short* __restrict__ hT,
                                      const void* __restrict__ a_src, const void* __restrict__ a_dst,
                                      float* __restrict__ srcv, float* __restrict__ dstv) {
  const int t = blockIdx.x * 256 + threadIdx.x;      // (bh, n), n fastest
  const int n = t & 2047, bh = t >> 11, hh = bh & 3;
  const unsigned short* col = hT + (size_t)bh * 32 * 2048 + n;
  float s = 0.f, d = 0.f;
#pragma unroll
  for (int dd = 0; dd < 32; ++dd) {
    const float v = bfu_to_f(col[(size_t)dd * 2048]);
    s += v * ldS<F32>(a_src, hh * 32 + dd);
    d += v * ldS<F32>(a_dst, hh * 32 + dd);
  }
  srcv[t] = s * LOG2E; dstv[t] = d * LOG2E;          // exp(x) = exp2(x*log2e)
}
__global__ __launch_bounds__(256) void k_sd(const unsigned short* hT, const void* a_src,
                                            const void* a_dst, float* srcv, float* dstv,
                                            const void* adj) {
  if (detect_f32(adj)) k_sd_body<true>(hT, a_src, a_dst, srcv, dstv);
  else                 k_sd_body<false>(hT, a_src, a_dst, srcv, dstv);
}

// ---------------- Kernel 2: paired-bh LDS double-buffered flash GAT attention ------
// Block = 512 thr (8 waves) = 2 bh x one i64-tile: waves 0-3 -> bh0, 4-7 -> bh1.
// adj tile is IDENTICAL for all bh -> staged once, shared (halves staging).
// vt + dst' per sub, double-buffered; one barrier per 128-j chunk.
// den on the MFMA pipe (ones-A fragment). 2 blocks/CU = 4 waves/SIMD.
struct SmemAttn {
  unsigned short adj[2][64][132];      // 33792 B  [buf][i-local][j], stride 66 dw (=2 mod 32)
  unsigned short vt[2][2][32][132];    // 33792 B  [buf][sub][d][j]
  float dst[2][2][128];                //  2048 B  [buf][sub][j-chunk]
};                                     // 69632 B -> 2 blocks/CU

template<bool F32> DEV void k_attn_body(SmemAttn& sm, const void* __restrict__ adjv,
                                        const unsigned short* __restrict__ hT,
                                        const float* __restrict__ srcv,
                                        const float* __restrict__ dstv,
                                        unsigned short* __restrict__ ao) {
  const int tid = threadIdx.x, lane = tid & 63, wave = tid >> 6;
  const int bhp = blockIdx.x & 15, i64 = blockIdx.x >> 4;  // bhp-fast: 16 blocks share adj tile
  const int sub = wave >> 2, w4 = wave & 3;
  const int bh = bhp * 2 + sub;
  const int b = bh >> 2, hh = bh & 3;
  const int m = lane & 15, q = lane >> 4;
  const int i0 = i64 * 64;
  const int il = w4 * 16 + m;                              // lane's local i-row (0..63)

  // staging maps
  const int arow = tid >> 3, acol = (tid & 7) * 16;        // adj: 64 rows x 8 thr x 16 elems
  const int vsub = tid >> 8, vd = (tid >> 3) & 31, vcol = (tid & 7) * 16;  // vt
  const bool dstg = (tid & 7) == 0;                        // dst: 64 stagers spread over waves
  const int dk = tid >> 3, dsub = dk >> 5, dj = (dk & 31) * 4;

  f32x4 fr[4];   // F32 adj prefetch (16 floats)
  i32x4 br[2];   // BF16 adj prefetch
  i32x4 vr[2];   // V^T prefetch
  f32x4 dr;      // dst chunk prefetch (stagers only)

  // ---- prologue: stage chunk 0 into buf 0 ----
  {
    const size_t ga = (size_t)(i0 + arow) * 2048 + acol;
    i32x4 w0, w1;
    if constexpr (F32) {
#pragma unroll
      for (int p = 0; p < 4; ++p) fr[p] = *(const f32x4*)((const float*)adjv + ga + p * 4);
      w0[0]=(int)pack_bf_rtz(fr[0][0],fr[0][1]); w0[1]=(int)pack_bf_rtz(fr[0][2],fr[0][3]);
      w0[2]=(int)pack_bf_rtz(fr[1][0],fr[1][1]); w0[3]=(int)pack_bf_rtz(fr[1][2],fr[1][3]);
      w1[0]=(int)pack_bf_rtz(fr[2][0],fr[2][1]); w1[1]=(int)pack_bf_rtz(fr[2][2],fr[2][3]);
      w1[2]=(int)pack_bf_rtz(fr[3][0],fr[3][1]); w1[3]=(int)pack_bf_rtz(fr[3][2],fr[3][3]);
    } else {
      w0 = *(const i32x4*)((const unsigned short*)adjv + ga);
      w1 = *(const i32x4*)((const unsigned short*)adjv + ga + 8);
    }
    *(i32x4*)&sm.adj[0][arow][acol]     = w0;
    *(i32x4*)&sm.adj[0][arow][acol + 8] = w1;
    const unsigned short* vp = hT + ((size_t)((bhp * 2 + vsub) * 32 + vd)) * 2048 + vcol;
    *(i32x4*)&sm.vt[0][vsub][vd][vcol]     = *(const i32x4*)vp;
    *(i32x4*)&sm.vt[0][vsub][vd][vcol + 8] = *(const i32x4*)(vp + 8);
    if (dstg)
      *(f32x4*)&sm.dst[0][dsub][dj] = *(const f32x4*)(dstv + (size_t)(bhp * 2 + dsub) * 2048 + dj);
  }
  __syncthreads();

  const float src_i = srcv[bh * 2048 + i0 + il];
  f32x4 acc0 = {0.f,0.f,0.f,0.f}, acc1 = {0.f,0.f,0.f,0.f};
  f32x4 acc2 = {0.f,0.f,0.f,0.f};                          // den accumulator (ones-A MFMA)
  i32x4 ones4;
  ones4[0] = ones4[1] = ones4[2] = ones4[3] = (int)0x3F803F80u;
  const bf16x8 Aones = __builtin_bit_cast(bf16x8, ones4);

  for (int c = 0; c < 16; ++c) {
    const int cb = c & 1;
    const bool pf = (c < 15);
    if (pf) {                                   // issue chunk c+1 loads (coalesced)
      const int j1 = (c + 1) * 128;
      const size_t ga = (size_t)(i0 + arow) * 2048 + j1 + acol;
      if constexpr (F32) {
#pragma unroll
        for (int p = 0; p < 4; ++p) fr[p] = *(const f32x4*)((const float*)adjv + ga + p * 4);
      } else {
        br[0] = *(const i32x4*)((const unsigned short*)adjv + ga);
        br[1] = *(const i32x4*)((const unsigned short*)adjv + ga + 8);
      }
      const unsigned short* vp = hT + ((size_t)((bhp * 2 + vsub) * 32 + vd)) * 2048 + j1 + vcol;
      vr[0] = *(const i32x4*)vp;
      vr[1] = *(const i32x4*)(vp + 8);
      if (dstg)
        dr = *(const f32x4*)(dstv + (size_t)(bhp * 2 + dsub) * 2048 + j1 + dj);
    }
    // ---- compute 4 x 32-j on buf cb ----
#pragma unroll
    for (int jc = 0; jc < 4; ++jc) {
      const int jq = jc * 32 + q * 8;
      i32x4 aw = *(const i32x4*)&sm.adj[cb][il][jq];
      f32x4 d0 = *(const f32x4*)&sm.dst[cb][sub][jq];
      f32x4 d1 = *(const f32x4*)&sm.dst[cb][sub][jq + 4];
      bf16x8 A0 = *(const bf16x8*)&sm.vt[cb][sub][m][jq];
      bf16x8 A1 = *(const bf16x8*)&sm.vt[cb][sub][16 + m][jq];
      float a[8];
#pragma unroll
      for (int t = 0; t < 4; ++t) {
        unsigned int w = (unsigned int)aw[t];
        a[2*t]   = __builtin_bit_cast(float, w << 16);
        a[2*t+1] = __builtin_bit_cast(float, w & 0xffff0000u);
      }
      float p[8];
#pragma unroll
      for (int pp = 0; pp < 8; ++pp) {
        const float s = src_i + ((pp < 4) ? d0[pp] : d1[pp - 4]);     // log2-domain score
        const float l = fmaxf(s, 0.2f * s);                           // leaky: 0.2s>s iff s<0
        p[pp] = a[pp] * exp2f(l);                                     // bare v_exp_f32
      }
      i32x4 pk4;
      pk4[0] = (int)pack_bf_rtz(p[0], p[1]);
      pk4[1] = (int)pack_bf_rtz(p[2], p[3]);
      pk4[2] = (int)pack_bf_rtz(p[4], p[5]);
      pk4[3] = (int)pack_bf_rtz(p[6], p[7]);
      const bf16x8 pkv = __builtin_bit_cast(bf16x8, pk4);
      acc0 = __builtin_amdgcn_mfma_f32_16x16x32_bf16(A0, pkv, acc0, 0, 0, 0);
      acc1 = __builtin_amdgcn_mfma_f32_16x16x32_bf16(A1, pkv, acc1, 0, 0, 0);
      acc2 = __builtin_amdgcn_mfma_f32_16x16x32_bf16(Aones, pkv, acc2, 0, 0, 0);
    }
    if (pf) {                                   // write chunk c+1 into the other buffer
      const int nb = cb ^ 1;
      i32x4 w0, w1;
      if constexpr (F32) {
        w0[0]=(int)pack_bf_rtz(fr[0][0],fr[0][1]); w0[1]=(int)pack_bf_rtz(fr[0][2],fr[0][3]);
        w0[2]=(int)pack_bf_rtz(fr[1][0],fr[1][1]); w0[3]=(int)pack_bf_rtz(fr[1][2],fr[1][3]);
        w1[0]=(int)pack_bf_rtz(fr[2][0],fr[2][1]); w1[1]=(int)pack_bf_rtz(fr[2][2],fr[2][3]);
        w1[2]=(int)pack_bf_rtz(fr[3][0],fr[3][1]); w1[3]=(int)pack_bf_rtz(fr[3][2],fr[3][3]);
      } else { w0 = br[0]; w1 = br[1]; }
      *(i32x4*)&sm.adj[nb][arow][acol]     = w0;
      *(i32x4*)&sm.adj[nb][arow][acol + 8] = w1;
      *(i32x4*)&sm.vt[nb][vsub][vd][vcol]     = vr[0];
      *(i32x4*)&sm.vt[nb][vsub][vd][vcol + 8] = vr[1];
      if (dstg) *(f32x4*)&sm.dst[nb][dsub][dj] = dr;
    }
    __syncthreads();
  }

  // den for row i=m is acc2[r] (identical for all r, all q) -- no shuffles needed.
  const float inv = 1.f / fmaxf(acc2[0], 1e-20f);

  // D: col = m = i, row = q*4+r = d. Lane writes channels q*4..+3 and 16+q*4..+3.
  unsigned short* op = ao + ((size_t)(b * 2048) + i0 + il) * 128 + hh * 32 + q * 4;
  u32x2 w0, w1;
  w0[0] = pack_bf_rne(acc0[0] * inv, acc0[1] * inv);
  w0[1] = pack_bf_rne(acc0[2] * inv, acc0[3] * inv);
  w1[0] = pack_bf_rne(acc1[0] * inv, acc1[1] * inv);
  w1[1] = pack_bf_rne(acc1[2] * inv, acc1[3] * inv);
  *(u32x2*)op        = w0;
  *(u32x2*)(op + 16) = w1;
}
__global__ __launch_bounds__(512, 4) void k_attn(const void* adj, const unsigned short* hT,
                                                 const float* srcv, const float* dstv,
                                                 unsigned short* ao) {
  __shared__ __align__(16) SmemAttn sm;          // ONE allocation for both instantiations
  if (detect_f32(adj)) k_attn_body<true>(sm, adj, hT, srcv, dstv, ao);
  else                 k_attn_body<false>(sm, adj, hT, srcv, dstv, ao);
}

// ---------------- Kernel 3: y = LN(ao @ Wo^T + bo + x) ----------------
template<bool F32> DEV void k_out_body(const unsigned short* __restrict__ ao,
                                       const void* __restrict__ Wo, const void* __restrict__ bo,
                                       const void* __restrict__ x, const void* __restrict__ gamma,
                                       const void* __restrict__ beta, void* __restrict__ out,
                                       float (&y_s)[16][132]) {
  const int tid = threadIdx.x, lane = tid & 63, wave = tid >> 6;
  const int m = lane & 15, q = lane >> 4;
  const int rbase = blockIdx.x * 16;
  bf16x8 af[4];
#pragma unroll
  for (int k = 0; k < 4; ++k)
    af[k] = ldfrag<false>(ao, ((size_t)(rbase + m)) * 128 + q * 8 + k * 32);
  f32x4 acc[2] = {{0.f,0.f,0.f,0.f},{0.f,0.f,0.f,0.f}};
#pragma unroll
  for (int ct = 0; ct < 2; ++ct) {
    const size_t wrow = (size_t)(wave * 32 + ct * 16 + m) * 128 + q * 8;
#pragma unroll
    for (int k = 0; k < 4; ++k)
      acc[ct] = __builtin_amdgcn_mfma_f32_16x16x32_bf16(af[k], ldfrag<F32>(Wo, wrow + k * 32),
                                                        acc[ct], 0, 0, 0);
  }
#pragma unroll
  for (int ct = 0; ct < 2; ++ct) {
    const int c = wave * 32 + ct * 16 + m;
    const float bov = ldS<F32>(bo, c);
#pragma unroll
    for (int r = 0; r < 4; ++r) {
      const int row = q * 4 + r;
      y_s[row][c] = acc[ct][r] + bov + ldS<F32>(x, (size_t)(rbase + row) * 128 + c);
    }
  }
  __syncthreads();
  const int r = tid >> 4, c16 = tid & 15;
  float vals[8], sum = 0.f, sq = 0.f;
#pragma unroll
  for (int k = 0; k < 8; ++k) {
    const float v = y_s[r][c16 * 8 + k];
    vals[k] = v; sum += v; sq += v * v;
  }
#pragma unroll
  for (int msk = 1; msk < 16; msk <<= 1) {
    sum += __shfl_xor(sum, msk, 16);
    sq  += __shfl_xor(sq,  msk, 16);
  }
  const float mu  = sum * (1.f / 128.f);
  const float var = fmaxf(sq * (1.f / 128.f) - mu * mu, 0.f);
  const float rstd = rsqrtf(var + 1e-5f);
  float o[8];
#pragma unroll
  for (int k = 0; k < 8; ++k) {
    const int c = c16 * 8 + k;
    o[k] = (vals[k] - mu) * rstd * ldS<F32>(gamma, c) + ldS<F32>(beta, c);
  }
  const size_t obase = (size_t)(rbase + r) * 128 + c16 * 8;
  if constexpr (F32) {
    float* op = (float*)out + obase;
    f32x4 w0 = {o[0],o[1],o[2],o[3]}, w1 = {o[4],o[5],o[6],o[7]};
    *(f32x4*)op = w0; *(f32x4*)(op + 4) = w1;
  } else {
    union { unsigned short u[8]; i32x4 v; } ob;
#pragma unroll
    for (int k = 0; k < 8; ++k) ob.u[k] = f_to_bf(o[k]);
    *(i32x4*)((unsigned short*)out + obase) = ob.v;
  }
}
__global__ __launch_bounds__(256) void k_out(const unsigned short* ao, const void* Wo,
                                             const void* bo, const void* x, const void* gamma,
                                             const void* beta, void* out, const void* adj) {
  __shared__ __align__(16) float y_s[16][132];   // shared across both instantiations
  if (detect_f32(adj)) k_out_body<true>(ao, Wo, bo, x, gamma, beta, out, y_s);
  else                 k_out_body<false>(ao, Wo, bo, x, gamma, beta, out, y_s);
}

// ---------------- launch ----------------
extern "C" void kernel_launch(void* const* d_in, const int* in_sizes, int n_in,
                              void* d_out, int out_size, void* d_ws, size_t ws_size,
                              hipStream_t stream) {
  const void* x     = d_in[0];
  const void* adj   = d_in[1];
  const void* W     = d_in[2];
  const void* a_src = d_in[3];
  const void* a_dst = d_in[4];
  const void* Wo    = d_in[5];
  const void* bo    = d_in[6];
  const void* gamma = d_in[7];
  const void* beta  = d_in[8];

  char* ws = (char*)d_ws;
  unsigned short* hT_ws  = (unsigned short*)ws;              // 4,194,304 B  bf16 hT (BH*32, N)
  unsigned short* ao_ws  = (unsigned short*)(ws + 4194304);  // 4,194,304 B  bf16 attn out (B,N,128)
  float*          src_ws = (float*)(ws + 8388608);           // 262,144 B    fp32 src' (BH,N)
  float*          dst_ws = (float*)(ws + 8650752);           // 262,144 B    fp32 dst' (BH,N)

  k_h   <<<1024, 256, 0, stream>>>(x, W, hT_ws, adj);
  k_sd  <<<256,  256, 0, stream>>>(hT_ws, a_src, a_dst, src_ws, dst_ws, adj);
  k_attn<<<512,  512, 0, stream>>>(adj, hT_ws, src_ws, dst_ws, ao_ws);
  k_out <<<1024, 256, 0, stream>>>(ao_ws, Wo, bo, x, gamma, beta, d_out, adj);
}

// Round 11
// 166.948 us; speedup vs baseline: 1.1959x; 1.0461x over previous
//
#include <hip/hip_runtime.h>

typedef short bf16x8 __attribute__((ext_vector_type(8)));   // 8 bf16 in 4 VGPRs
typedef float f32x4  __attribute__((ext_vector_type(4)));
typedef float f32x2  __attribute__((ext_vector_type(2)));
typedef int   i32x4  __attribute__((ext_vector_type(4)));
typedef unsigned int u32x2 __attribute__((ext_vector_type(2)));

#define DEV static __device__ __forceinline__
#define LOG2E 1.4426950408889634f

DEV float bfu_to_f(unsigned short s) { return __builtin_bit_cast(float, (unsigned int)s << 16); }
DEV unsigned short f_to_bf(float f) {                 // RNE fp32 -> bf16
  unsigned int u = __builtin_bit_cast(unsigned int, f);
  u += 0x7fffu + ((u >> 16) & 1u);
  return (unsigned short)(u >> 16);
}
DEV unsigned int pack_bf_rne(float lo, float hi) {
  return (unsigned int)f_to_bf(lo) | ((unsigned int)f_to_bf(hi) << 16);
}
// RTZ pack of two f32 -> (bf16(hi)<<16)|bf16(lo): one v_perm_b32
DEV unsigned int pack_bf_rtz(float lo, float hi) {
#if __has_builtin(__builtin_amdgcn_perm)
  return __builtin_amdgcn_perm(__builtin_bit_cast(unsigned int, hi),
                               __builtin_bit_cast(unsigned int, lo), 0x07060302u);
#else
  return (__builtin_bit_cast(unsigned int, hi) & 0xffff0000u) |
         (__builtin_bit_cast(unsigned int, lo) >> 16);
#endif
}
// guaranteed-native exp2 (single v_exp_f32)
DEV float nexp2(float x) {
#if __has_builtin(__builtin_amdgcn_exp2f)
  return __builtin_amdgcn_exp2f(x);
#else
  return exp2f(x);
#endif
}

// dtype discriminator: adj[0][0] == 1.0 exactly. fp32 word0 == 0x3F800000;
// bf16 word0 low halfword = 0x3F80 != 0 -> never equal.
DEV bool detect_f32(const void* adj) { return ((const float*)adj)[0] == 1.0f; }

template<bool F32> DEV float ldS(const void* p, size_t i) {
  if constexpr (F32) return ((const float*)p)[i];
  else               return bfu_to_f(((const unsigned short*)p)[i]);
}
template<bool F32> DEV void ld8f(const void* p, size_t i, float* o) {
  if constexpr (F32) {
    const float* f = (const float*)p + i;
    f32x4 a = *(const f32x4*)f, b = *(const f32x4*)(f + 4);
    o[0]=a[0]; o[1]=a[1]; o[2]=a[2]; o[3]=a[3];
    o[4]=b[0]; o[5]=b[1]; o[6]=b[2]; o[7]=b[3];
  } else {
    i32x4 w = *(const i32x4*)((const unsigned short*)p + i);
#pragma unroll
    for (int k = 0; k < 4; ++k) {
      unsigned int u = (unsigned int)w[k];
      o[2*k]   = __builtin_bit_cast(float, u << 16);
      o[2*k+1] = __builtin_bit_cast(float, u & 0xffff0000u);
    }
  }
}
template<bool F32> DEV bf16x8 ldfrag(const void* p, size_t i) {
  if constexpr (F32) {
    float o[8]; ld8f<true>(p, i, o);
    union { bf16x8 v; unsigned short u[8]; } r;
#pragma unroll
    for (int k = 0; k < 8; ++k) r.u[k] = f_to_bf(o[k]);
    return r.v;
  } else {
    return __builtin_bit_cast(bf16x8, *(const i32x4*)((const unsigned short*)p + i));
  }
}

// ---------------- Kernel 1: hT[(b*4+hh)*32+d][n] = (x@W^T) transposed, bf16 ----------
template<bool F32> DEV void k_h_body(const void* __restrict__ x, const void* __restrict__ W,
                                     unsigned short* __restrict__ hT,
                                     unsigned short (&t_s)[16][136]) {
  const int tid = threadIdx.x, lane = tid & 63, wave = tid >> 6;
  const int nt = blockIdx.x >> 3, ct = blockIdx.x & 7;    // 128 nt x 8 ct
  const int m = lane & 15, q = lane >> 4;
  bf16x8 wf[4];
#pragma unroll
  for (int k = 0; k < 4; ++k)
    wf[k] = ldfrag<F32>(W, (size_t)(ct * 16 + m) * 128 + q * 8 + k * 32);
#pragma unroll
  for (int s = 0; s < 2; ++s) {
    const int nsub = wave * 2 + s;
    const size_t xr = (size_t)(nt * 128 + nsub * 16 + m) * 128 + q * 8;
    f32x4 acc = {0.f, 0.f, 0.f, 0.f};
#pragma unroll
    for (int k = 0; k < 4; ++k)
      acc = __builtin_amdgcn_mfma_f32_16x16x32_bf16(ldfrag<F32>(x, xr + k * 32), wf[k],
                                                    acc, 0, 0, 0);
    u32x2 w2; w2[0] = pack_bf_rne(acc[0], acc[1]); w2[1] = pack_bf_rne(acc[2], acc[3]);
    *(u32x2*)&t_s[m][nsub * 16 + q * 4] = w2;
  }
  __syncthreads();
  const int row = tid >> 4, c8 = tid & 15;
  const int chg = ct * 16 + row, hh = chg >> 5, dloc = chg & 31;
  const int ng = nt * 128 + c8 * 8, b = ng >> 11, nl = ng & 2047;
  i32x4 v = *(const i32x4*)&t_s[row][c8 * 8];
  *(i32x4*)(hT + ((size_t)((b * 4 + hh) * 32 + dloc)) * 2048 + nl) = v;
}
__global__ __launch_bounds__(256) void k_h(const void* x, const void* W,
                                           unsigned short* hT, const void* adj) {
  __shared__ __align__(16) unsigned short t_s[16][136];   // shared across both instantiations
  if (detect_f32(adj)) k_h_body<true>(x, W, hT, t_s); else k_h_body<false>(x, W, hT, t_s);
}

// ---------------- Kernel 1b: src/dst projections (pre-scaled by log2e) ----------------
template<bool F32> DEV void k_sd_body(const unsigned short* __restrict__ hT,
                                      const void* __restrict__ a_src, const void* __restrict__ a_dst,
                                      float* __restrict__ srcv, float* __restrict__ dstv) {
  const int t = blockIdx.x * 256 + threadIdx.x;      // (bh, n), n fastest
  const int n = t & 2047, bh = t >> 11, hh = bh & 3;
  const unsigned short* col = hT + (size_t)bh * 32 * 2048 + n;
  float s = 0.f, d = 0.f;
#pragma unroll
  for (int dd = 0; dd < 32; ++dd) {
    const float v = bfu_to_f(col[(size_t)dd * 2048]);
    s += v * ldS<F32>(a_src, hh * 32 + dd);
    d += v * ldS<F32>(a_dst, hh * 32 + dd);
  }
  srcv[t] = s * LOG2E; dstv[t] = d * LOG2E;          // exp(x) = exp2(x*log2e)
}
__global__ __launch_bounds__(256) void k_sd(const unsigned short* hT, const void* a_src,
                                            const void* a_dst, float* srcv, float* dstv,
                                            const void* adj) {
  if (detect_f32(adj)) k_sd_body<true>(hT, a_src, a_dst, srcv, dstv);
  else                 k_sd_body<false>(hT, a_src, a_dst, srcv, dstv);
}

// ---------------- Kernel 2: paired-bh LDS double-buffered flash GAT attention ------
// Block = 512 thr (8 waves) = 2 bh x one i64-tile: waves 0-3 -> bh0, 4-7 -> bh1.
// adj tile is IDENTICAL for all bh -> staged once, shared. vt + dst' per sub,
// double-buffered; one barrier per 128-j chunk. den on the MFMA pipe (ones-A).
// Score math on f32x2 ext-vectors -> v_pk_add/mul/max_f32 (halves score VALU);
// exp via __builtin_amdgcn_exp2f (guaranteed bare v_exp_f32).
struct SmemAttn {
  unsigned short adj[2][64][132];      // 33792 B  [buf][i-local][j], stride 66 dw (=2 mod 32)
  unsigned short vt[2][2][32][132];    // 33792 B  [buf][sub][d][j]
  float dst[2][2][128];                //  2048 B  [buf][sub][j-chunk]
};                                     // 69632 B -> 2 blocks/CU

template<bool F32> DEV void k_attn_body(SmemAttn& sm, const void* __restrict__ adjv,
                                        const unsigned short* __restrict__ hT,
                                        const float* __restrict__ srcv,
                                        const float* __restrict__ dstv,
                                        unsigned short* __restrict__ ao) {
  const int tid = threadIdx.x, lane = tid & 63, wave = tid >> 6;
  const int bhp = blockIdx.x & 15, i64 = blockIdx.x >> 4;  // bhp-fast: 16 blocks share adj tile
  const int sub = wave >> 2, w4 = wave & 3;
  const int bh = bhp * 2 + sub;
  const int b = bh >> 2, hh = bh & 3;
  const int m = lane & 15, q = lane >> 4;
  const int i0 = i64 * 64;
  const int il = w4 * 16 + m;                              // lane's local i-row (0..63)

  // staging maps
  const int arow = tid >> 3, acol = (tid & 7) * 16;        // adj: 64 rows x 8 thr x 16 elems
  const int vsub = tid >> 8, vd = (tid >> 3) & 31, vcol = (tid & 7) * 16;  // vt
  const bool dstg = (tid & 7) == 0;                        // dst: 64 stagers spread over waves
  const int dk = tid >> 3, dsub = dk >> 5, dj = (dk & 31) * 4;

  f32x4 fr[4];   // F32 adj prefetch (16 floats)
  i32x4 br[2];   // BF16 adj prefetch
  i32x4 vr[2];   // V^T prefetch
  f32x4 dr;      // dst chunk prefetch (stagers only)

  // ---- prologue: stage chunk 0 into buf 0 ----
  {
    const size_t ga = (size_t)(i0 + arow) * 2048 + acol;
    i32x4 w0, w1;
    if constexpr (F32) {
#pragma unroll
      for (int p = 0; p < 4; ++p) fr[p] = *(const f32x4*)((const float*)adjv + ga + p * 4);
      w0[0]=(int)pack_bf_rtz(fr[0][0],fr[0][1]); w0[1]=(int)pack_bf_rtz(fr[0][2],fr[0][3]);
      w0[2]=(int)pack_bf_rtz(fr[1][0],fr[1][1]); w0[3]=(int)pack_bf_rtz(fr[1][2],fr[1][3]);
      w1[0]=(int)pack_bf_rtz(fr[2][0],fr[2][1]); w1[1]=(int)pack_bf_rtz(fr[2][2],fr[2][3]);
      w1[2]=(int)pack_bf_rtz(fr[3][0],fr[3][1]); w1[3]=(int)pack_bf_rtz(fr[3][2],fr[3][3]);
    } else {
      w0 = *(const i32x4*)((const unsigned short*)adjv + ga);
      w1 = *(const i32x4*)((const unsigned short*)adjv + ga + 8);
    }
    *(i32x4*)&sm.adj[0][arow][acol]     = w0;
    *(i32x4*)&sm.adj[0][arow][acol + 8] = w1;
    const unsigned short* vp = hT + ((size_t)((bhp * 2 + vsub) * 32 + vd)) * 2048 + vcol;
    *(i32x4*)&sm.vt[0][vsub][vd][vcol]     = *(const i32x4*)vp;
    *(i32x4*)&sm.vt[0][vsub][vd][vcol + 8] = *(const i32x4*)(vp + 8);
    if (dstg)
      *(f32x4*)&sm.dst[0][dsub][dj] = *(const f32x4*)(dstv + (size_t)(bhp * 2 + dsub) * 2048 + dj);
  }
  __syncthreads();

  const float src_i = srcv[bh * 2048 + i0 + il];
  const f32x2 src2 = {src_i, src_i};
  f32x4 acc0 = {0.f,0.f,0.f,0.f}, acc1 = {0.f,0.f,0.f,0.f};
  f32x4 acc2 = {0.f,0.f,0.f,0.f};                          // den accumulator (ones-A MFMA)
  i32x4 ones4;
  ones4[0] = ones4[1] = ones4[2] = ones4[3] = (int)0x3F803F80u;
  const bf16x8 Aones = __builtin_bit_cast(bf16x8, ones4);

  for (int c = 0; c < 16; ++c) {
    const int cb = c & 1;
    const bool pf = (c < 15);
    if (pf) {                                   // issue chunk c+1 loads (coalesced)
      const int j1 = (c + 1) * 128;
      const size_t ga = (size_t)(i0 + arow) * 2048 + j1 + acol;
      if constexpr (F32) {
#pragma unroll
        for (int p = 0; p < 4; ++p) fr[p] = *(const f32x4*)((const float*)adjv + ga + p * 4);
      } else {
        br[0] = *(const i32x4*)((const unsigned short*)adjv + ga);
        br[1] = *(const i32x4*)((const unsigned short*)adjv + ga + 8);
      }
      const unsigned short* vp = hT + ((size_t)((bhp * 2 + vsub) * 32 + vd)) * 2048 + j1 + vcol;
      vr[0] = *(const i32x4*)vp;
      vr[1] = *(const i32x4*)(vp + 8);
      if (dstg)
        dr = *(const f32x4*)(dstv + (size_t)(bhp * 2 + dsub) * 2048 + j1 + dj);
    }
    // ---- compute 4 x 32-j on buf cb (packed-f32 score math) ----
#pragma unroll
    for (int jc = 0; jc < 4; ++jc) {
      const int jq = jc * 32 + q * 8;
      i32x4 aw = *(const i32x4*)&sm.adj[cb][il][jq];
      f32x4 d0 = *(const f32x4*)&sm.dst[cb][sub][jq];
      f32x4 d1 = *(const f32x4*)&sm.dst[cb][sub][jq + 4];
      bf16x8 A0 = *(const bf16x8*)&sm.vt[cb][sub][m][jq];
      bf16x8 A1 = *(const bf16x8*)&sm.vt[cb][sub][16 + m][jq];
      i32x4 pk4;
#pragma unroll
      for (int t = 0; t < 4; ++t) {
        unsigned int w = (unsigned int)aw[t];                 // adj elems j = jq+2t, jq+2t+1
        f32x2 av;
        av[0] = __builtin_bit_cast(float, w << 16);
        av[1] = __builtin_bit_cast(float, w & 0xffff0000u);
        f32x2 dv;
        dv[0] = (t < 2) ? d0[2*t]     : d1[2*(t-2)];
        dv[1] = (t < 2) ? d0[2*t + 1] : d1[2*(t-2) + 1];
        const f32x2 sv = src2 + dv;                           // v_pk_add_f32
        const f32x2 lv = __builtin_elementwise_max(sv, 0.2f * sv);  // v_pk_mul + v_pk_max
        f32x2 ev; ev[0] = nexp2(lv[0]); ev[1] = nexp2(lv[1]); // 2x v_exp_f32
        const f32x2 pv = av * ev;                             // v_pk_mul_f32
        pk4[t] = (int)pack_bf_rtz(pv[0], pv[1]);              // v_perm
      }
      const bf16x8 pkv = __builtin_bit_cast(bf16x8, pk4);
      acc0 = __builtin_amdgcn_mfma_f32_16x16x32_bf16(A0, pkv, acc0, 0, 0, 0);
      acc1 = __builtin_amdgcn_mfma_f32_16x16x32_bf16(A1, pkv, acc1, 0, 0, 0);
      acc2 = __builtin_amdgcn_mfma_f32_16x16x32_bf16(Aones, pkv, acc2, 0, 0, 0);
    }
    if (pf) {                                   // write chunk c+1 into the other buffer
      const int nb = cb ^ 1;
      i32x4 w0, w1;
      if constexpr (F32) {
        w0[0]=(int)pack_bf_rtz(fr[0][0],fr[0][1]); w0[1]=(int)pack_bf_rtz(fr[0][2],fr[0][3]);
        w0[2]=(int)pack_bf_rtz(fr[1][0],fr[1][1]); w0[3]=(int)pack_bf_rtz(fr[1][2],fr[1][3]);
        w1[0]=(int)pack_bf_rtz(fr[2][0],fr[2][1]); w1[1]=(int)pack_bf_rtz(fr[2][2],fr[2][3]);
        w1[2]=(int)pack_bf_rtz(fr[3][0],fr[3][1]); w1[3]=(int)pack_bf_rtz(fr[3][2],fr[3][3]);
      } else { w0 = br[0]; w1 = br[1]; }
      *(i32x4*)&sm.adj[nb][arow][acol]     = w0;
      *(i32x4*)&sm.adj[nb][arow][acol + 8] = w1;
      *(i32x4*)&sm.vt[nb][vsub][vd][vcol]     = vr[0];
      *(i32x4*)&sm.vt[nb][vsub][vd][vcol + 8] = vr[1];
      if (dstg) *(f32x4*)&sm.dst[nb][dsub][dj] = dr;
    }
    __syncthreads();
  }

  // den for row i=m is acc2[r] (identical for all r, all q) -- no shuffles needed.
  const float inv = 1.f / fmaxf(acc2[0], 1e-20f);

  // D: col = m = i, row = q*4+r = d. Lane writes channels q*4..+3 and 16+q*4..+3.
  unsigned short* op = ao + ((size_t)(b * 2048) + i0 + il) * 128 + hh * 32 + q * 4;
  u32x2 w0, w1;
  w0[0] = pack_bf_rne(acc0[0] * inv, acc0[1] * inv);
  w0[1] = pack_bf_rne(acc0[2] * inv, acc0[3] * inv);
  w1[0] = pack_bf_rne(acc1[0] * inv, acc1[1] * inv);
  w1[1] = pack_bf_rne(acc1[2] * inv, acc1[3] * inv);
  *(u32x2*)op        = w0;
  *(u32x2*)(op + 16) = w1;
}
__global__ __launch_bounds__(512, 4) void k_attn(const void* adj, const unsigned short* hT,
                                                 const float* srcv, const float* dstv,
                                                 unsigned short* ao) {
  __shared__ __align__(16) SmemAttn sm;          // ONE allocation for both instantiations
  if (detect_f32(adj)) k_attn_body<true>(sm, adj, hT, srcv, dstv, ao);
  else                 k_attn_body<false>(sm, adj, hT, srcv, dstv, ao);
}

// ---------------- Kernel 3: y = LN(ao @ Wo^T + bo + x) ----------------
template<bool F32> DEV void k_out_body(const unsigned short* __restrict__ ao,
                                       const void* __restrict__ Wo, const void* __restrict__ bo,
                                       const void* __restrict__ x, const void* __restrict__ gamma,
                                       const void* __restrict__ beta, void* __restrict__ out,
                                       float (&y_s)[16][132]) {
  const int tid = threadIdx.x, lane = tid & 63, wave = tid >> 6;
  const int m = lane & 15, q = lane >> 4;
  const int rbase = blockIdx.x * 16;
  bf16x8 af[4];
#pragma unroll
  for (int k = 0; k < 4; ++k)
    af[k] = ldfrag<false>(ao, ((size_t)(rbase + m)) * 128 + q * 8 + k * 32);
  f32x4 acc[2] = {{0.f,0.f,0.f,0.f},{0.f,0.f,0.f,0.f}};
#pragma unroll
  for (int ct = 0; ct < 2; ++ct) {
    const size_t wrow = (size_t)(wave * 32 + ct * 16 + m) * 128 + q * 8;
#pragma unroll
    for (int k = 0; k < 4; ++k)
      acc[ct] = __builtin_amdgcn_mfma_f32_16x16x32_bf16(af[k], ldfrag<F32>(Wo, wrow + k * 32),
                                                        acc[ct], 0, 0, 0);
  }
#pragma unroll
  for (int ct = 0; ct < 2; ++ct) {
    const int c = wave * 32 + ct * 16 + m;
    const float bov = ldS<F32>(bo, c);
#pragma unroll
    for (int r = 0; r < 4; ++r) {
      const int row = q * 4 + r;
      y_s[row][c] = acc[ct][r] + bov + ldS<F32>(x, (size_t)(rbase + row) * 128 + c);
    }
  }
  __syncthreads();
  const int r = tid >> 4, c16 = tid & 15;
  float vals[8], sum = 0.f, sq = 0.f;
#pragma unroll
  for (int k = 0; k < 8; ++k) {
    const float v = y_s[r][c16 * 8 + k];
    vals[k] = v; sum += v; sq += v * v;
  }
#pragma unroll
  for (int msk = 1; msk < 16; msk <<= 1) {
    sum += __shfl_xor(sum, msk, 16);
    sq  += __shfl_xor(sq,  msk, 16);
  }
  const float mu  = sum * (1.f / 128.f);
  const float var = fmaxf(sq * (1.f / 128.f) - mu * mu, 0.f);
  const float rstd = rsqrtf(var + 1e-5f);
  float o[8];
#pragma unroll
  for (int k = 0; k < 8; ++k) {
    const int c = c16 * 8 + k;
    o[k] = (vals[k] - mu) * rstd * ldS<F32>(gamma, c) + ldS<F32>(beta, c);
  }
  const size_t obase = (size_t)(rbase + r) * 128 + c16 * 8;
  if constexpr (F32) {
    float* op = (float*)out + obase;
    f32x4 w0 = {o[0],o[1],o[2],o[3]}, w1 = {o[4],o[5],o[6],o[7]};
    *(f32x4*)op = w0; *(f32x4*)(op + 4) = w1;
  } else {
    union { unsigned short u[8]; i32x4 v; } ob;
#pragma unroll
    for (int k = 0; k < 8; ++k) ob.u[k] = f_to_bf(o[k]);
    *(i32x4*)((unsigned short*)out + obase) = ob.v;
  }
}
__global__ __launch_bounds__(256) void k_out(const unsigned short* ao, const void* Wo,
                                             const void* bo, const void* x, const void* gamma,
                                             const void* beta, void* out, const void* adj) {
  __shared__ __align__(16) float y_s[16][132];   // shared across both instantiations
  if (detect_f32(adj)) k_out_body<true>(ao, Wo, bo, x, gamma, beta, out, y_s);
  else                 k_out_body<false>(ao, Wo, bo, x, gamma, beta, out, y_s);
}

// ---------------- launch ----------------
extern "C" void kernel_launch(void* const* d_in, const int* in_sizes, int n_in,
                              void* d_out, int out_size, void* d_ws, size_t ws_size,
                              hipStream_t stream) {
  const void* x     = d_in[0];
  const void* adj   = d_in[1];
  const void* W     = d_in[2];
  const void* a_src = d_in[3];
  const void* a_dst = d_in[4];
  const void* Wo    = d_in[5];
  const void* bo    = d_in[6];
  const void* gamma = d_in[7];
  const void* beta  = d_in[8];

  char* ws = (char*)d_ws;
  unsigned short* hT_ws  = (unsigned short*)ws;              // 4,194,304 B  bf16 hT (BH*32, N)
  unsigned short* ao_ws  = (unsigned short*)(ws + 4194304);  // 4,194,304 B  bf16 attn out (B,N,128)
  float*          src_ws = (float*)(ws + 8388608);           // 262,144 B    fp32 src' (BH,N)
  float*          dst_ws = (float*)(ws + 8650752);           // 262,144 B    fp32 dst' (BH,N)

  k_h   <<<1024, 256, 0, stream>>>(x, W, hT_ws, adj);
  k_sd  <<<256,  256, 0, stream>>>(hT_ws, a_src, a_dst, src_ws, dst_ws, adj);
  k_attn<<<512,  512, 0, stream>>>(adj, hT_ws, src_ws, dst_ws, ao_ws);
  k_out <<<1024, 256, 0, stream>>>(ao_ws, Wo, bo, x, gamma, beta, d_out, adj);
}